// Round 1
// baseline (22917.996 us; speedup 1.0000x reference)
//
#include <hip/hip_runtime.h>
#include <stdint.h>

#define B_ 64
#define T_ 512
#define D_ 256
#define U_ 512
#define C_ 4
#define KTOT 768      // 512 (h) + 256 (x) concatenated K
#define KBLKS 96      // KTOT/8 16B-blocks
#define AROW 97       // padded 16B-blocks per A row (bank-conflict pad)
#define NSTEPS 512

typedef unsigned short u16;
typedef unsigned int u32;
typedef __attribute__((ext_vector_type(8))) short short8;
typedef __attribute__((ext_vector_type(4))) float f32x4;

__device__ __forceinline__ u16 f2bf(float f) {
  union { float f; u32 u; } v; v.f = f;
  u32 r = v.u + 0x7fffu + ((v.u >> 16) & 1u);   // RNE
  return (u16)(r >> 16);
}
__device__ __forceinline__ float bf2f(u16 b) {
  union { u32 u; float f; } v; v.u = ((u32)b) << 16;
  return v.f;
}
__device__ __forceinline__ float sigm(float x) {
  return 1.0f / (1.0f + __expf(-x));
}
__device__ __forceinline__ void gload_lds16(const void* g, void* l) {
  __builtin_amdgcn_global_load_lds(
      (const __attribute__((address_space(1))) u32*)g,
      (__attribute__((address_space(3))) u32*)l, 16, 0, 0);
}

// ---- prep: pack W = [Wh; Wx] (K=768) per (cell,gate) into bf16, k-packed-8 layout [c2g][kblk][n][8]
__global__ void prep_w(const float* __restrict__ Wjh, const float* __restrict__ Wjx,
                       const float* __restrict__ Wkh, const float* __restrict__ Wkx,
                       u16* __restrict__ Wp) {
  int w = blockIdx.x * 256 + threadIdx.x;     // < C_*2*KBLKS*512 = 393216
  int n = w & 511;
  int kb = (w >> 9) % KBLKS;
  int cg = (w >> 9) / KBLKS;                  // c*2+g
  int g = cg & 1, c = cg >> 1;
  const float* Wh = g ? Wkh : Wjh;
  const float* Wx = g ? Wkx : Wjx;
  u16 tmp[8] __attribute__((aligned(16)));
  #pragma unroll
  for (int e = 0; e < 8; ++e) {
    int k = kb * 8 + e;
    float f = (k < 512) ? Wh[((size_t)c * 512 + k) * 512 + n]
                        : Wx[((size_t)c * 256 + (k - 512)) * 512 + n];
    tmp[e] = f2bf(f);
  }
  *(uint4*)(Wp + (size_t)w * 8) = *(const uint4*)tmp;
}

// ---- prep: x -> bf16 hi/lo pair
__global__ void prep_x(const float* __restrict__ x, u16* __restrict__ xhl) {
  size_t idx = (size_t)blockIdx.x * 256 + threadIdx.x;  // < 8388608, flat [b][t][d]
  float v = x[idx];
  u16 hi = f2bf(v);
  u16 lo = f2bf(v - bf2f(hi));
  xhl[idx] = hi;
  xhl[idx + 8388608] = lo;
}

// ---- prep: h0 -> bf16 hi/lo into buffer 0
__global__ void prep_h(const float* __restrict__ h0, u16* __restrict__ hbuf) {
  size_t idx = (size_t)blockIdx.x * 256 + threadIdx.x;  // < 131072, flat [c][b][u]
  int u = idx & 511; int b = (idx >> 9) & 63; int c = idx >> 15;
  float v = h0[idx];
  u16 hi = f2bf(v), lo = f2bf(v - bf2f(hi));
  hbuf[((size_t)(c * 2 + 0) * 64 + b) * 512 + u] = hi;
  hbuf[((size_t)(c * 2 + 1) * 64 + b) * 512 + u] = lo;
}

// ---- prep: combined biases bjx+bjh, bkx+bkh
__global__ void prep_bias(const float* __restrict__ bjx, const float* __restrict__ bjh,
                          const float* __restrict__ bkx, const float* __restrict__ bkh,
                          float* __restrict__ biasf) {
  int idx = blockIdx.x * 256 + threadIdx.x;  // < 4096
  int u = idx & 511; int g = (idx >> 9) & 1; int c = idx >> 10;
  float v = g ? (bkx[c * 512 + u] + bkh[c * 512 + u])
              : (bjx[c * 512 + u] + bjh[c * 512 + u]);
  biasf[(size_t)(c * 2 + g) * 512 + u] = v;
}

// ---- the scan: 256 WGs = 4 cells x 4 row-blocks(16) x 16 col-slices(32)
// Per step: stage A=[h_hi|h_lo, x_hi|x_lo] rows into LDS, MFMA 16x16x32 bf16 (2 passes),
// sigmoid gate update, write seq slot into d_out, group barrier (16 WGs sharing rows).
__global__ void __launch_bounds__(256, 1)
scan(const u16* __restrict__ Wp, const u16* __restrict__ xhl,
     u16* __restrict__ hbuf, const float* __restrict__ biasf,
     int* __restrict__ cnt, float* __restrict__ out) {
  __shared__ __attribute__((aligned(16))) u16 Blds[2][KBLKS][32][8];   // 98304 B
  __shared__ __attribute__((aligned(16))) u16 Alds[2][16][AROW][8];    // 49664 B
  __shared__ __attribute__((aligned(16))) float pre_lds[2][2][16][17]; // 8704 B

  const int wg = blockIdx.x;
  const int c = wg >> 6, mb = (wg >> 4) & 3, nb = wg & 15;
  const int group = wg >> 4;                  // c*4+mb: the 16 nb-WGs share batch rows
  const int tid = threadIdx.x;
  const int wave = tid >> 6, lane = tid & 63;
  const int ntile = wave & 1, gate = wave >> 1;
  const int m16 = lane & 15, quad = lane >> 4;

  // Load weight slice once: both gates, K=768, 32 columns [nb*32, nb*32+32)
  {
    uint4* Bl = (uint4*)&Blds[0][0][0][0];
    const uint4* Wg = (const uint4*)Wp;
    for (int i = 0; i < 24; ++i) {
      int w = tid + i * 256;                  // 0..6143
      int g2 = w / 3072, rem = w - g2 * 3072;
      int kb = rem >> 5, nl = rem & 31;
      Bl[w] = Wg[(size_t)((c * 2 + g2) * KBLKS + kb) * 512 + nb * 32 + nl];
    }
  }

  const int bl_ = tid >> 4, un_ = tid & 15;
  const int u0 = nb * 32 + un_, u1 = u0 + 16;
  const float bj0 = biasf[(c * 2 + 0) * 512 + u0], bj1 = biasf[(c * 2 + 0) * 512 + u1];
  const float bk0 = biasf[(c * 2 + 1) * 512 + u0], bk1 = biasf[(c * 2 + 1) * 512 + u1];
  const int bg = mb * 16 + bl_;

  __syncthreads();

  for (int t = 0; t < NSTEPS; ++t) {
    const u16* hc = hbuf + (size_t)(t & 1) * 524288;
    u16* hn = hbuf + (size_t)((t + 1) & 1) * 524288;

    // Stage A, h part: 32 rows (hl,m) via global_load_lds (1 KB row = 64 lanes x 16B)
    for (int i = 0; i < 8; ++i) {
      int idx = wave * 8 + i;
      int hl = idx >> 4, m = idx & 15;
      const u16* src = hc + ((size_t)(c * 2 + hl) * 64 + (mb * 16 + m)) * 512;
      gload_lds16((const char*)src + lane * 16, &Alds[hl][m][0][0]);
    }
    // Stage A, x part: 32 rows x 512 B via vector loads
    {
      int xrow = tid >> 3, part = tid & 7;
      int hl = xrow >> 4, m = xrow & 15;
      const u16* src = xhl + (size_t)hl * 8388608 +
                       ((size_t)(mb * 16 + m) * 512 + t) * 256;
      #pragma unroll
      for (int i = 0; i < 4; ++i) {
        int blk = part * 4 + i;
        *(uint4*)&Alds[hl][m][64 + blk][0] = *(const uint4*)(src + blk * 8);
      }
    }
    __syncthreads();

    // MFMA: wave -> (gate, ntile) 16x16 tile, K=768, 2 passes (h hi + lo)
    f32x4 acc = {0.f, 0.f, 0.f, 0.f};
    #pragma unroll
    for (int ks = 0; ks < 24; ++ks) {
      int kb = ks * 4 + quad;
      short8 ah = *(const short8*)&Alds[0][m16][kb][0];
      short8 al = *(const short8*)&Alds[1][m16][kb][0];
      short8 bb = *(const short8*)&Blds[gate][kb][ntile * 16 + m16][0];
      acc = __builtin_amdgcn_mfma_f32_16x16x32_bf16(ah, bb, acc, 0, 0, 0);
      acc = __builtin_amdgcn_mfma_f32_16x16x32_bf16(al, bb, acc, 0, 0, 0);
    }
    // C/D layout: col=lane&15, row=quad*4+reg (m89-verified)
    #pragma unroll
    for (int r = 0; r < 4; ++r)
      pre_lds[gate][ntile][quad * 4 + r][m16] = acc[r];
    __syncthreads();

    // Gate update: 2 outputs per thread
    #pragma unroll
    for (int half = 0; half < 2; ++half) {
      int u = half ? u1 : u0;
      float pj = pre_lds[0][half][bl_][un_] + (half ? bj1 : bj0);
      float pk = pre_lds[1][half][bl_][un_] + (half ? bk1 : bk0);
      float ho = bf2f(Alds[0][bl_][u >> 3][u & 7]) + bf2f(Alds[1][bl_][u >> 3][u & 7]);
      float jj = sigm(pj), kk = sigm(pk);
      float hnew = jj * (1.0f - ho) + (1.0f - kk) * ho;
      // seq slot c of the oscillator output block
      out[((size_t)bg * 2560 + (size_t)t * 5 + c) * 512 + u] = hnew;
      u16 hi = f2bf(hnew);
      u16 lo = f2bf(hnew - bf2f(hi));
      hn[((size_t)(c * 2 + 0) * 64 + bg) * 512 + u] = hi;
      hn[((size_t)(c * 2 + 1) * 64 + bg) * 512 + u] = lo;
    }

    // Group barrier: 16 WGs sharing these batch rows
    __threadfence();
    __syncthreads();
    if (tid == 0) {
      int* cp = cnt + group * NSTEPS + t;
      __hip_atomic_fetch_add(cp, 1, __ATOMIC_RELEASE, __HIP_MEMORY_SCOPE_AGENT);
      while (__hip_atomic_load(cp, __ATOMIC_ACQUIRE, __HIP_MEMORY_SCOPE_AGENT) < 16) {
        __builtin_amdgcn_s_sleep(2);
      }
      __threadfence();   // belt-and-braces L1 invalidate before next staging
    }
    __syncthreads();
  }
}

// ---- oscillator: slots 0..3 hold phi,omega,r,mu; write z0..z4 in place (per-thread RAW only)
__global__ void osc(float* __restrict__ out) {
  size_t idx = (size_t)blockIdx.x * 256 + threadIdx.x;  // < 4194304
  int u4 = idx & 127;
  int t = (int)((idx >> 7) & 511);
  int b = (int)(idx >> 16);
  float* base = out + ((size_t)b * 2560 + (size_t)t * 5) * 512 + (size_t)u4 * 4;
  float phi[4] __attribute__((aligned(16)));
  float om[4]  __attribute__((aligned(16)));
  float r[4]   __attribute__((aligned(16)));
  float mu[4]  __attribute__((aligned(16)));
  float z[4]   __attribute__((aligned(16)));
  *(float4*)phi = *(const float4*)(base);
  *(float4*)om  = *(const float4*)(base + 512);
  *(float4*)r   = *(const float4*)(base + 1024);
  *(float4*)mu  = *(const float4*)(base + 1536);
  #pragma unroll
  for (int e = 0; e < 4; ++e) z[e] = r[e] * __cosf(phi[e]);
  *(float4*)(base) = *(const float4*)z;
  #pragma unroll
  for (int s = 1; s < 5; ++s) {
    #pragma unroll
    for (int e = 0; e < 4; ++e) {
      r[e] = r[e] + (mu[e] - r[e] * r[e]) * r[e];
      phi[e] = phi[e] + om[e];
      z[e] = r[e] * __cosf(phi[e]);
    }
    *(float4*)(base + (size_t)s * 512) = *(const float4*)z;
  }
}

extern "C" void kernel_launch(void* const* d_in, const int* in_sizes, int n_in,
                              void* d_out, int out_size, void* d_ws, size_t ws_size,
                              hipStream_t stream) {
  const float* x   = (const float*)d_in[0];
  const float* h0  = (const float*)d_in[1];
  const float* Wjx = (const float*)d_in[2];
  const float* bjx = (const float*)d_in[3];
  const float* Wjh = (const float*)d_in[4];
  const float* bjh = (const float*)d_in[5];
  const float* Wkx = (const float*)d_in[6];
  const float* bkx = (const float*)d_in[7];
  const float* Wkh = (const float*)d_in[8];
  const float* bkh = (const float*)d_in[9];
  float* out = (float*)d_out;

  // ws layout (~42 MB total)
  char* ws = (char*)d_ws;
  u16* Wp      = (u16*)(ws + 0);          // 6,291,456 B packed weights
  u16* xhl     = (u16*)(ws + 6291456);    // 33,554,432 B x hi/lo
  u16* hbuf    = (u16*)(ws + 39845888);   // 2,097,152 B h double buffer
  float* biasf = (float*)(ws + 41943040); // 16,384 B
  int* cnt     = (int*)(ws + 41959424);   // 32,768 B barrier counters

  hipMemsetAsync(cnt, 0, 16 * NSTEPS * sizeof(int), stream);
  prep_w<<<1536, 256, 0, stream>>>(Wjh, Wjx, Wkh, Wkx, Wp);
  prep_x<<<32768, 256, 0, stream>>>(x, xhl);
  prep_h<<<512, 256, 0, stream>>>(h0, hbuf);
  prep_bias<<<16, 256, 0, stream>>>(bjx, bjh, bkx, bkh, biasf);
  scan<<<256, 256, 0, stream>>>(Wp, xhl, hbuf, biasf, cnt, out);
  osc<<<16384, 256, 0, stream>>>(out);
}

// Round 2
// 1960.402 us; speedup vs baseline: 11.6905x; 11.6905x over previous
//
#include <hip/hip_runtime.h>
#include <stdint.h>

#define B_ 64
#define T_ 512
#define D_ 256
#define U_ 512
#define C_ 4
#define KTOT 768      // 512 (h) + 256 (x) concatenated K
#define KBLKS 96      // KTOT/8 16B-blocks
#define AROW 97       // padded 16B-blocks per A row (bank-conflict pad)
#define NSTEPS 512

typedef unsigned short u16;
typedef unsigned int u32;
typedef __attribute__((ext_vector_type(8))) short short8;
typedef __attribute__((ext_vector_type(4))) float f32x4;

__device__ __forceinline__ u16 f2bf(float f) {
  union { float f; u32 u; } v; v.f = f;
  u32 r = v.u + 0x7fffu + ((v.u >> 16) & 1u);   // RNE
  return (u16)(r >> 16);
}
__device__ __forceinline__ float bf2f(u16 b) {
  union { u32 u; float f; } v; v.u = ((u32)b) << 16;
  return v.f;
}
__device__ __forceinline__ float sigm(float x) {
  return 1.0f / (1.0f + __expf(-x));
}
// AUX: CPol bits. 0 = cached; 17 = SC0|SC1 (read at device/system coherence
// point, per-line — avoids buffer_inv L2-invalidate storms).
template <int AUX>
__device__ __forceinline__ void gload_lds16(const void* g, void* l) {
  __builtin_amdgcn_global_load_lds(
      (const __attribute__((address_space(1))) u32*)g,
      (__attribute__((address_space(3))) u32*)l, 16, 0, AUX);
}

// ---- prep: pack W = [Wh; Wx] (K=768) per (cell,gate) into bf16, k-packed-8 layout [c2g][kblk][n][8]
__global__ void prep_w(const float* __restrict__ Wjh, const float* __restrict__ Wjx,
                       const float* __restrict__ Wkh, const float* __restrict__ Wkx,
                       u16* __restrict__ Wp) {
  int w = blockIdx.x * 256 + threadIdx.x;     // < C_*2*KBLKS*512 = 393216
  int n = w & 511;
  int kb = (w >> 9) % KBLKS;
  int cg = (w >> 9) / KBLKS;                  // c*2+g
  int g = cg & 1, c = cg >> 1;
  const float* Wh = g ? Wkh : Wjh;
  const float* Wx = g ? Wkx : Wjx;
  u16 tmp[8] __attribute__((aligned(16)));
  #pragma unroll
  for (int e = 0; e < 8; ++e) {
    int k = kb * 8 + e;
    float f = (k < 512) ? Wh[((size_t)c * 512 + k) * 512 + n]
                        : Wx[((size_t)c * 256 + (k - 512)) * 512 + n];
    tmp[e] = f2bf(f);
  }
  *(uint4*)(Wp + (size_t)w * 8) = *(const uint4*)tmp;
}

// ---- prep: x -> bf16 hi/lo pair
__global__ void prep_x(const float* __restrict__ x, u16* __restrict__ xhl) {
  size_t idx = (size_t)blockIdx.x * 256 + threadIdx.x;  // < 8388608, flat [b][t][d]
  float v = x[idx];
  u16 hi = f2bf(v);
  u16 lo = f2bf(v - bf2f(hi));
  xhl[idx] = hi;
  xhl[idx + 8388608] = lo;
}

// ---- prep: h0 -> bf16 hi/lo into buffer 0
__global__ void prep_h(const float* __restrict__ h0, u16* __restrict__ hbuf) {
  size_t idx = (size_t)blockIdx.x * 256 + threadIdx.x;  // < 131072, flat [c][b][u]
  int u = idx & 511; int b = (idx >> 9) & 63; int c = idx >> 15;
  float v = h0[idx];
  u16 hi = f2bf(v), lo = f2bf(v - bf2f(hi));
  hbuf[((size_t)(c * 2 + 0) * 64 + b) * 512 + u] = hi;
  hbuf[((size_t)(c * 2 + 1) * 64 + b) * 512 + u] = lo;
}

// ---- prep: combined biases bjx+bjh, bkx+bkh
__global__ void prep_bias(const float* __restrict__ bjx, const float* __restrict__ bjh,
                          const float* __restrict__ bkx, const float* __restrict__ bkh,
                          float* __restrict__ biasf) {
  int idx = blockIdx.x * 256 + threadIdx.x;  // < 4096
  int u = idx & 511; int g = (idx >> 9) & 1; int c = idx >> 10;
  float v = g ? (bkx[c * 512 + u] + bkh[c * 512 + u])
              : (bjx[c * 512 + u] + bjh[c * 512 + u]);
  biasf[(size_t)(c * 2 + g) * 512 + u] = v;
}

// ---- the scan: 256 WGs = 4 cells x 4 row-blocks(16) x 16 col-slices(32)
// Cross-WG h exchange: write-through relaxed agent atomics (NO fences — agent
// acquire/release would buffer_inv/buffer_wbl2 the whole L2 per step, which
// was the round-1 44 us/step disaster). Visibility chain: sc1 stores ->
// __syncthreads drains vmcnt -> relaxed fetch_add -> consumer relaxed poll ->
// consumer reads with SC0|SC1 (coherence-point reads).
__global__ void __launch_bounds__(256, 1)
scan(const u16* __restrict__ Wp, const u16* __restrict__ xhl,
     u16* __restrict__ hbuf, const float* __restrict__ biasf,
     int* __restrict__ cnt, float* __restrict__ out) {
  __shared__ __attribute__((aligned(16))) u16 Blds[2][KBLKS][32][8];   // 98304 B
  __shared__ __attribute__((aligned(16))) u16 Alds[2][16][AROW][8];    // 49664 B
  __shared__ __attribute__((aligned(16))) float pre_lds[2][2][16][17]; // 8704 B

  const int wg = blockIdx.x;
  const int c = wg >> 6, mb = (wg >> 4) & 3, nb = wg & 15;
  const int group = wg >> 4;                  // c*4+mb: the 16 nb-WGs share batch rows
  const int tid = threadIdx.x;
  const int wave = tid >> 6, lane = tid & 63;
  const int ntile = wave & 1, gate = wave >> 1;
  const int m16 = lane & 15, quad = lane >> 4;

  // Load weight slice once: both gates, K=768, 32 columns [nb*32, nb*32+32)
  {
    uint4* Bl = (uint4*)&Blds[0][0][0][0];
    const uint4* Wg = (const uint4*)Wp;
    for (int i = 0; i < 24; ++i) {
      int w = tid + i * 256;                  // 0..6143
      int g2 = w / 3072, rem = w - g2 * 3072;
      int kb = rem >> 5, nl = rem & 31;
      Bl[w] = Wg[(size_t)((c * 2 + g2) * KBLKS + kb) * 512 + nb * 32 + nl];
    }
  }

  const int bl_ = tid >> 4, un_ = tid & 15;
  const int half = un_ >> 3;                  // which 16-col MFMA tile
  const int u_lo = nb * 32 + un_ * 2;         // this thread's adjacent col pair
  const int c0 = (un_ * 2) & 15, c1 = c0 + 1; // cols within the tile
  const float bj0 = biasf[(c * 2 + 0) * 512 + u_lo], bj1 = biasf[(c * 2 + 0) * 512 + u_lo + 1];
  const float bk0 = biasf[(c * 2 + 1) * 512 + u_lo], bk1 = biasf[(c * 2 + 1) * 512 + u_lo + 1];
  const int bg = mb * 16 + bl_;
  u32* hbuf32 = (u32*)hbuf;

  // x staging geometry (32 rows = 2 planes x 16 batch rows, 512 B each)
  const int xrow = tid >> 3, xpart = tid & 7;
  const int xhl_pl = xrow >> 4, xm = xrow & 15;

  __syncthreads();

  // Pre-stage x for t=0
  {
    const u16* src = xhl + (size_t)xhl_pl * 8388608 +
                     ((size_t)(mb * 16 + xm) * 512 + 0) * 256;
    #pragma unroll
    for (int i = 0; i < 4; ++i) {
      int blk = xpart * 4 + i;
      *(uint4*)&Alds[xhl_pl][xm][64 + blk][0] = *(const uint4*)(src + blk * 8);
    }
  }

  for (int t = 0; t < NSTEPS; ++t) {
    const u16* hc = hbuf + (size_t)(t & 1) * 524288;
    u32* hn32 = hbuf32 + (size_t)((t + 1) & 1) * 262144;

    // Stage A, h part: 32 rows (hl,m) via global_load_lds, coherence-point read
    for (int i = 0; i < 8; ++i) {
      int idx = wave * 8 + i;
      int hl = idx >> 4, m = idx & 15;
      const u16* src = hc + ((size_t)(c * 2 + hl) * 64 + (mb * 16 + m)) * 512;
      gload_lds16<17>((const char*)src + lane * 16, &Alds[hl][m][0][0]);
    }
    __syncthreads();

    // MFMA: wave -> (gate, ntile) 16x16 tile, K=768, 2 passes (h hi + lo)
    f32x4 acc = {0.f, 0.f, 0.f, 0.f};
    #pragma unroll
    for (int ks = 0; ks < 24; ++ks) {
      int kb = ks * 4 + quad;
      short8 ah = *(const short8*)&Alds[0][m16][kb][0];
      short8 al = *(const short8*)&Alds[1][m16][kb][0];
      short8 bb = *(const short8*)&Blds[gate][kb][ntile * 16 + m16][0];
      acc = __builtin_amdgcn_mfma_f32_16x16x32_bf16(ah, bb, acc, 0, 0, 0);
      acc = __builtin_amdgcn_mfma_f32_16x16x32_bf16(al, bb, acc, 0, 0, 0);
    }
    // C/D layout: col=lane&15, row=quad*4+reg (m89-verified)
    #pragma unroll
    for (int r = 0; r < 4; ++r)
      pre_lds[gate][ntile][quad * 4 + r][m16] = acc[r];
    __syncthreads();

    // Overlap: stage x for t+1 (touches only LDS chunks 64..95; h region and
    // pre_lds untouched, so safe alongside the gate update).
    {
      int tn = (t + 1 < NSTEPS) ? t + 1 : 0;
      const u16* src = xhl + (size_t)xhl_pl * 8388608 +
                       ((size_t)(mb * 16 + xm) * 512 + tn) * 256;
      #pragma unroll
      for (int i = 0; i < 4; ++i) {
        int blk = xpart * 4 + i;
        *(uint4*)&Alds[xhl_pl][xm][64 + blk][0] = *(const uint4*)(src + blk * 8);
      }
    }

    // Gate update: adjacent col pair (u_lo, u_lo+1)
    {
      float pj0 = pre_lds[0][half][bl_][c0] + bj0;
      float pj1 = pre_lds[0][half][bl_][c1] + bj1;
      float pk0 = pre_lds[1][half][bl_][c0] + bk0;
      float pk1 = pre_lds[1][half][bl_][c1] + bk1;
      int ua = u_lo, ub = u_lo + 1;
      float hoa = bf2f(Alds[0][bl_][ua >> 3][ua & 7]) + bf2f(Alds[1][bl_][ua >> 3][ua & 7]);
      float hob = bf2f(Alds[0][bl_][ub >> 3][ub & 7]) + bf2f(Alds[1][bl_][ub >> 3][ub & 7]);
      float hn0 = sigm(pj0) * (1.0f - hoa) + (1.0f - sigm(pk0)) * hoa;
      float hn1 = sigm(pj1) * (1.0f - hob) + (1.0f - sigm(pk1)) * hob;
      float2 z; z.x = hn0; z.y = hn1;
      *(float2*)&out[((size_t)bg * 2560 + (size_t)t * 5 + c) * 512 + u_lo] = z;
      u16 h0h = f2bf(hn0), h1h = f2bf(hn1);
      u16 h0l = f2bf(hn0 - bf2f(h0h)), h1l = f2bf(hn1 - bf2f(h1h));
      u32 hip = (u32)h0h | ((u32)h1h << 16);
      u32 lop = (u32)h0l | ((u32)h1l << 16);
      size_t i0 = ((size_t)(c * 2 + 0) * 64 + bg) * 256 + nb * 16 + un_;
      size_t i1 = ((size_t)(c * 2 + 1) * 64 + bg) * 256 + nb * 16 + un_;
      __hip_atomic_store(&hn32[i0], hip, __ATOMIC_RELAXED, __HIP_MEMORY_SCOPE_AGENT);
      __hip_atomic_store(&hn32[i1], lop, __ATOMIC_RELAXED, __HIP_MEMORY_SCOPE_AGENT);
    }

    // Group barrier: 16 WGs sharing these batch rows. __syncthreads drains
    // vmcnt (write-through stores visible) before the relaxed arrive.
    __syncthreads();
    if (tid == 0) {
      int* cp = cnt + group * NSTEPS + t;
      __hip_atomic_fetch_add(cp, 1, __ATOMIC_RELAXED, __HIP_MEMORY_SCOPE_AGENT);
      while (__hip_atomic_load(cp, __ATOMIC_RELAXED, __HIP_MEMORY_SCOPE_AGENT) < 16) {
        __builtin_amdgcn_s_sleep(2);
      }
    }
    __syncthreads();
  }
}

// ---- oscillator: slots 0..3 hold phi,omega,r,mu; write z0..z4 in place (per-thread RAW only)
__global__ void osc(float* __restrict__ out) {
  size_t idx = (size_t)blockIdx.x * 256 + threadIdx.x;  // < 4194304
  int u4 = idx & 127;
  int t = (int)((idx >> 7) & 511);
  int b = (int)(idx >> 16);
  float* base = out + ((size_t)b * 2560 + (size_t)t * 5) * 512 + (size_t)u4 * 4;
  float phi[4] __attribute__((aligned(16)));
  float om[4]  __attribute__((aligned(16)));
  float r[4]   __attribute__((aligned(16)));
  float mu[4]  __attribute__((aligned(16)));
  float z[4]   __attribute__((aligned(16)));
  *(float4*)phi = *(const float4*)(base);
  *(float4*)om  = *(const float4*)(base + 512);
  *(float4*)r   = *(const float4*)(base + 1024);
  *(float4*)mu  = *(const float4*)(base + 1536);
  #pragma unroll
  for (int e = 0; e < 4; ++e) z[e] = r[e] * __cosf(phi[e]);
  *(float4*)(base) = *(const float4*)z;
  #pragma unroll
  for (int s = 1; s < 5; ++s) {
    #pragma unroll
    for (int e = 0; e < 4; ++e) {
      r[e] = r[e] + (mu[e] - r[e] * r[e]) * r[e];
      phi[e] = phi[e] + om[e];
      z[e] = r[e] * __cosf(phi[e]);
    }
    *(float4*)(base + (size_t)s * 512) = *(const float4*)z;
  }
}

extern "C" void kernel_launch(void* const* d_in, const int* in_sizes, int n_in,
                              void* d_out, int out_size, void* d_ws, size_t ws_size,
                              hipStream_t stream) {
  const float* x   = (const float*)d_in[0];
  const float* h0  = (const float*)d_in[1];
  const float* Wjx = (const float*)d_in[2];
  const float* bjx = (const float*)d_in[3];
  const float* Wjh = (const float*)d_in[4];
  const float* bjh = (const float*)d_in[5];
  const float* Wkx = (const float*)d_in[6];
  const float* bkx = (const float*)d_in[7];
  const float* Wkh = (const float*)d_in[8];
  const float* bkh = (const float*)d_in[9];
  float* out = (float*)d_out;

  // ws layout (~42 MB total)
  char* ws = (char*)d_ws;
  u16* Wp      = (u16*)(ws + 0);          // 6,291,456 B packed weights
  u16* xhl     = (u16*)(ws + 6291456);    // 33,554,432 B x hi/lo
  u16* hbuf    = (u16*)(ws + 39845888);   // 2,097,152 B h double buffer
  float* biasf = (float*)(ws + 41943040); // 16,384 B
  int* cnt     = (int*)(ws + 41959424);   // 32,768 B barrier counters

  hipMemsetAsync(cnt, 0, 16 * NSTEPS * sizeof(int), stream);
  prep_w<<<1536, 256, 0, stream>>>(Wjh, Wjx, Wkh, Wkx, Wp);
  prep_x<<<32768, 256, 0, stream>>>(x, xhl);
  prep_h<<<512, 256, 0, stream>>>(h0, hbuf);
  prep_bias<<<16, 256, 0, stream>>>(bjx, bjh, bkx, bkh, biasf);
  scan<<<256, 256, 0, stream>>>(Wp, xhl, hbuf, biasf, cnt, out);
  osc<<<16384, 256, 0, stream>>>(out);
}